// Round 6
// baseline (251.189 us; speedup 1.0000x reference)
//
#include <hip/hip_runtime.h>
#include <hip/hip_bf16.h>

typedef __attribute__((ext_vector_type(8))) short short8;
typedef __attribute__((ext_vector_type(4))) float floatx4;
typedef __attribute__((ext_vector_type(2))) float float2v;

__device__ __forceinline__ float leaky(float v){ return v > 0.f ? v : 0.1f*v; }
__device__ __forceinline__ void atomAdd(float* p, float v){ unsafeAtomicAdd(p, v); }
__device__ __forceinline__ short f2bf(float f){
  __hip_bfloat16 h = __float2bfloat16(f);
  return *reinterpret_cast<short*>(&h);
}

// Edge features for all 3 nets + fused conv1 (layer-1 message pass).
__global__ void efeat_conv1(const float* __restrict__ x, const int* __restrict__ ei,
                            const float* __restrict__ w1a, const float* __restrict__ b1a,
                            const float* __restrict__ w1b, const float* __restrict__ b1b,
                            const float* __restrict__ w1c, const float* __restrict__ b1c,
                            const float* __restrict__ c1w2, const float* __restrict__ c1b2,
                            short* __restrict__ ef2b, short* __restrict__ ef3b,
                            float* __restrict__ agg1, int E, int Epad){
  __shared__ float sm[4][64];
  int tid = threadIdx.x;
  int id = blockIdx.x*256 + tid;
  int e = id >> 6, j = id & 63;
  float v1 = 0.f;
  if (e < Epad){
    if (e >= E){ ef2b[id] = 0; ef3b[id] = 0; }
    else {
      int s = ei[e], d = ei[E+e];
      float a0 = x[d*4+1] - x[s*4+1];
      float a1 = x[d*4+2] - x[s*4+2];
      float a2 = x[d*4+3] - x[s*4+3];
      v1 = leaky(a0*w1a[j] + a1*w1a[64+j] + a2*w1a[128+j] + b1a[j]);
      ef2b[id] = f2bf(leaky(a0*w1b[j] + a1*w1b[64+j] + a2*w1b[128+j] + b1b[j]));
      ef3b[id] = f2bf(leaky(a0*w1c[j] + a1*w1c[64+j] + a2*w1c[128+j] + b1c[j]));
    }
  }
  sm[tid >> 6][j] = v1;
  __syncthreads();
  if (tid < 32){
    int le = tid >> 3, o = tid & 7;
    int ge = blockIdx.x*4 + le;
    if (ge < E){
      int s = ei[ge], d = ei[E+ge];
      float z[4];
      #pragma unroll
      for (int i=0;i<4;i++) z[i] = c1b2[i*8+o];
      for (int k=0;k<64;k++){
        float a = sm[le][k];
        #pragma unroll
        for (int i=0;i<4;i++) z[i] += a*c1w2[k*32 + i*8 + o];
      }
      float msg = 0.f;
      #pragma unroll
      for (int i=0;i<4;i++) msg += x[s*4+i]*leaky(z[i]);
      atomAdd(&agg1[d*8+o], msg);
    }
  }
}

// Pack BOTH w2 matrices into bf16 MFMA B-fragment order in one dispatch.
__global__ void pack_w2_all(const float* __restrict__ w2a, short* __restrict__ pa,
                            const float* __restrict__ w2b, short* __restrict__ pb){
  int bid = blockIdx.x;
  const float* w2; short* dst; int IC, OC, cbase;
  if (bid < 16){ w2 = w2a; dst = pa; IC = 8;  OC = 64;  cbase = bid*4; }
  else        { w2 = w2b; dst = pb; IC = 64; OC = 128; cbase = (bid-16)*4; }
  int lane = threadIdx.x & 63;
  int c = cbase + (threadIdx.x >> 6);
  int OT = OC/16;
  int kh = c & 1; int rem = c >> 1; int otg = rem % OT; int i = rem / OT;
  int n = lane & 15, q = lane >> 4;
  short out[8];
  #pragma unroll
  for (int j=0;j<8;j++){
    int k = kh*32 + q*8 + j;
    out[j] = f2bf(w2[(size_t)k*(IC*OC) + i*OC + otg*16 + n]);
  }
  *reinterpret_cast<short8*>(dst + (size_t)c*512 + lane*8) = *reinterpret_cast<short8*>(out);
}

// node update: h = leaky(agg + hin @ root + cb), in-place on agg
template<int IC, int OC>
__global__ void node_kernel(float* __restrict__ h, const float* __restrict__ hin,
                            const float* __restrict__ root, const float* __restrict__ cb, int N){
  int id = blockIdx.x*256 + threadIdx.x;
  if (id >= N*OC) return;
  int n = id / OC, o = id % OC;
  float v = h[id] + cb[o];
  const float* hi = hin + (size_t)n*IC;
  #pragma unroll
  for (int i=0;i<IC;i++) v += hi[i]*root[i*OC+o];
  h[id] = leaky(v);
}

// node3 + pool fused, LDS-tiled: root3 (32KB) + 16 h-rows staged; register pool acc.
__global__ __launch_bounds__(256)
void node3_pool(const float* __restrict__ agg, const float* __restrict__ hin,
                const float* __restrict__ root, const float* __restrict__ cb,
                const int* __restrict__ batch, float* __restrict__ g, int N){
  __shared__ float rootS[64*128];
  __shared__ float hrow[16][64];
  int t = threadIdx.x;
  #pragma unroll
  for (int r=0;r<8;r++){
    int idx = t + r*256;
    reinterpret_cast<float4*>(rootS)[idx] = reinterpret_cast<const float4*>(root)[idx];
  }
  int n0 = blockIdx.x*16;
  {
    int nn = t >> 4, c = (t & 15)*4;
    int n = n0 + nn;
    float4 hv = (n < N) ? *reinterpret_cast<const float4*>(hin + (size_t)n*64 + c)
                        : float4{0.f,0.f,0.f,0.f};
    hrow[nn][c+0]=hv.x; hrow[nn][c+1]=hv.y; hrow[nn][c+2]=hv.z; hrow[nn][c+3]=hv.w;
  }
  __syncthreads();
  int o = t & 127, np = t >> 7;
  float acc = 0.f; int cur = -1;
  for (int rep=0; rep<8; rep++){
    int nl = rep*2 + np; int n = n0 + nl;
    if (n >= N) break;
    int b = batch[n];
    if (b != cur){ if (cur >= 0) atomAdd(&g[cur*128+o], acc); acc = 0.f; cur = b; }
    float v = agg[(size_t)n*128 + o] + cb[o];
    #pragma unroll 16
    for (int i=0;i<64;i++) v += hrow[nl][i]*rootS[i*128+o];
    acc += leaky(v);
  }
  if (cur >= 0) atomAdd(&g[cur*128+o], acc);
}

// Generalized MFMA NNConv: ping-pong B buffers (no reg copies), packed-f32 epilogue.
template<int IC, int OC, int MB, int ICB>
__global__ __launch_bounds__(256)
void conv_mfma(const short* __restrict__ efb, const float* __restrict__ h,
               const int* __restrict__ ei, const short* __restrict__ w2p,
               const float* __restrict__ b2, float* __restrict__ agg, int E){
  constexpr int ME   = MB*16;
  constexpr int OT   = OC/16;
  constexpr int WOT  = OT/4;
  constexpr int NSPL = IC/ICB;
  __shared__ float hsT[ICB][ME];
  __shared__ int sdst[ME];
  int tid = threadIdx.x;
  int bi = blockIdx.x;
  int eb = (bi / NSPL) * ME;
  int i0 = (bi % NSPL) * ICB;

  { // stage h[src, i0:i0+ICB] transposed into hsT[i_local][e]
    int e = tid % ME;
    int ge = eb + e;
    bool valid = ge < E;
    int src = valid ? ei[ge] : 0;
    constexpr int CH  = 256/ME;
    constexpr int IPC = ICB/CH;
    int c = tid / ME;
    const float* hp = h + (size_t)src*IC + i0 + c*IPC;
    if constexpr (IPC == 8){
      #pragma unroll
      for (int half=0; half<2; half++){
        float4 hv = valid ? reinterpret_cast<const float4*>(hp)[half]
                          : float4{0.f,0.f,0.f,0.f};
        hsT[c*IPC + half*4 + 0][e] = hv.x;
        hsT[c*IPC + half*4 + 1][e] = hv.y;
        hsT[c*IPC + half*4 + 2][e] = hv.z;
        hsT[c*IPC + half*4 + 3][e] = hv.w;
      }
    } else {
      #pragma unroll
      for (int j=0;j<IPC;j++)
        hsT[c*IPC + j][e] = valid ? hp[j] : 0.f;
    }
    if (tid < ME) sdst[tid] = (eb + tid < E) ? ei[E + eb + tid] : -1;
  }
  __syncthreads();

  int lane = tid & 63;
  int wv = tid >> 6;
  int n = lane & 15, quad = lane >> 4;
  int o0 = wv * (OC/4);

  short8 A[MB][2];
  #pragma unroll
  for (int m=0;m<MB;m++)
    #pragma unroll
    for (int kh=0;kh<2;kh++)
      A[m][kh] = *reinterpret_cast<const short8*>(efb + (size_t)(eb + m*16 + n)*64 + kh*32 + quad*8);

  float2v msg[MB][WOT][2];
  #pragma unroll
  for (int m=0;m<MB;m++)
    #pragma unroll
    for (int t=0;t<WOT;t++){
      msg[m][t][0] = (float2v){0.f,0.f};
      msg[m][t][1] = (float2v){0.f,0.f};
    }

  auto loadB = [&](int ii, short8 (&Bt)[WOT][2], float (&bzt)[WOT]){
    int ig = i0 + ii;
    if (ig >= IC) ig = IC-1;              // clamped prefetch overrun (values unused)
    #pragma unroll
    for (int t=0;t<WOT;t++){
      int otg = (o0 >> 4) + t;
      #pragma unroll
      for (int kh=0;kh<2;kh++)
        Bt[t][kh] = *reinterpret_cast<const short8*>(w2p + ((size_t)((ig*OT + otg)*2 + kh) << 9) + lane*8);
      bzt[t] = b2[ig*OC + o0 + t*16 + n];
    }
  };
  auto compute = [&](int ii, short8 (&Bt)[WOT][2], float (&bzt)[WOT]){
    #pragma unroll
    for (int m=0;m<MB;m++){
      float4 hv = *reinterpret_cast<const float4*>(&hsT[ii][m*16 + quad*4]);
      float2v hvl = {hv.x, hv.y};
      float2v hvh = {hv.z, hv.w};
      #pragma unroll
      for (int t=0;t<WOT;t++){
        floatx4 z = {bzt[t], bzt[t], bzt[t], bzt[t]};
        z = __builtin_amdgcn_mfma_f32_16x16x32_bf16(A[m][0], Bt[t][0], z, 0, 0, 0);
        z = __builtin_amdgcn_mfma_f32_16x16x32_bf16(A[m][1], Bt[t][1], z, 0, 0, 0);
        float2v zl = {z[0], z[1]};
        float2v zh = {z[2], z[3]};
        float2v ll = __builtin_elementwise_max(zl, zl*0.1f);  // v_pk_mul + v_pk_max
        float2v lh = __builtin_elementwise_max(zh, zh*0.1f);
        msg[m][t][0] += hvl*ll;                               // v_pk_fma
        msg[m][t][1] += hvh*lh;
      }
    }
  };

  short8 B0[WOT][2], B1[WOT][2];
  float bz0[WOT], bz1[WOT];
  loadB(0, B0, bz0);
  #pragma unroll 2
  for (int i=0;i<ICB;i+=2){
    loadB(i+1, B1, bz1);
    compute(i, B0, bz0);
    loadB(i+2, B0, bz0);
    compute(i+1, B1, bz1);
  }

  #pragma unroll
  for (int m=0;m<MB;m++){
    #pragma unroll
    for (int r=0;r<4;r++){
      int d = sdst[m*16 + quad*4 + r];
      if (d >= 0){
        #pragma unroll
        for (int t=0;t<WOT;t++)
          atomAdd(&agg[(size_t)d*OC + o0 + t*16 + n], msg[m][t][r>>1][r&1]);
      }
    }
  }
}

// readout MLP: one block per graph
__global__ void head_kernel(const float* __restrict__ g,
                            const float* __restrict__ fc1w, const float* __restrict__ fc1b,
                            const float* __restrict__ fc2w, const float* __restrict__ fc2b,
                            const float* __restrict__ fc3w, const float* __restrict__ fc3b,
                            float* __restrict__ out){
  __shared__ float s1[128], s2[128];
  int gi = blockIdx.x, t = threadIdx.x;
  s1[t] = g[gi*128+t];
  __syncthreads();
  float v = fc1b[t];
  for (int i=0;i<128;i++) v += s1[i]*fc1w[i*128+t];
  s2[t] = leaky(v);
  __syncthreads();
  if (t < 64){
    float v2 = fc2b[t];
    for (int i=0;i<128;i++) v2 += s2[i]*fc2w[i*64+t];
    s1[t] = leaky(v2);
  }
  __syncthreads();
  if (t == 0){
    float v3 = fc3b[0];
    for (int i=0;i<64;i++) v3 += s1[i]*fc3w[i];
    out[gi] = v3;
  }
}

extern "C" void kernel_launch(void* const* d_in, const int* in_sizes, int n_in,
                              void* d_out, int out_size, void* d_ws, size_t ws_size,
                              hipStream_t stream) {
  const float* x      = (const float*)d_in[0];
  const int*   ei     = (const int*)  d_in[1];
  const int*   batch  = (const int*)  d_in[2];
  const float* en1_w1 = (const float*)d_in[3];  const float* en1_b1 = (const float*)d_in[4];
  const float* en1_w2 = (const float*)d_in[5];  const float* en1_b2 = (const float*)d_in[6];
  const float* en2_w1 = (const float*)d_in[7];  const float* en2_b1 = (const float*)d_in[8];
  const float* en2_w2 = (const float*)d_in[9];  const float* en2_b2 = (const float*)d_in[10];
  const float* en3_w1 = (const float*)d_in[11]; const float* en3_b1 = (const float*)d_in[12];
  const float* en3_w2 = (const float*)d_in[13]; const float* en3_b2 = (const float*)d_in[14];
  const float* root1  = (const float*)d_in[15]; const float* cb1    = (const float*)d_in[16];
  const float* root2  = (const float*)d_in[17]; const float* cb2    = (const float*)d_in[18];
  const float* root3  = (const float*)d_in[19]; const float* cb3    = (const float*)d_in[20];
  const float* fc1w   = (const float*)d_in[21]; const float* fc1b   = (const float*)d_in[22];
  const float* fc2w   = (const float*)d_in[23]; const float* fc2b   = (const float*)d_in[24];
  const float* fc3w   = (const float*)d_in[25]; const float* fc3b   = (const float*)d_in[26];
  float* out = (float*)d_out;

  const int N = in_sizes[0] / 4;
  const int E = in_sizes[1] / 2;
  const int G = 32;
  const int Epad = (E + 63) & ~63;

  short* ef2b = (short*)d_ws;
  short* ef3b = ef2b + (size_t)Epad*64;
  short* w2p2 = ef3b + (size_t)Epad*64;
  short* w2p3 = w2p2 + 8*4*2*512;            // 32768 shorts
  float* a1   = (float*)(w2p3 + 64*8*2*512); // 524288 shorts
  float* a2   = a1 + (size_t)N*8;
  float* a3   = a2 + (size_t)N*64;
  float* g    = a3 + (size_t)N*128;

  size_t zero_bytes = ((size_t)N*(8+64+128) + (size_t)G*128) * sizeof(float);
  hipMemsetAsync(a1, 0, zero_bytes, stream);

  efeat_conv1<<<Epad/4, 256, 0, stream>>>(
      x, ei, en1_w1, en1_b1, en2_w1, en2_b1, en3_w1, en3_b1,
      en1_w2, en1_b2, ef2b, ef3b, a1, E, Epad);

  pack_w2_all<<<272, 256, 0, stream>>>(en2_w2, w2p2, en3_w2, w2p3);

  node_kernel<4,8><<<(N*8 + 255)/256, 256, 0, stream>>>(a1, x, root1, cb1, N);

  conv_mfma<8,64,2,8><<<Epad/32, 256, 0, stream>>>(ef2b, a1, ei, w2p2, en2_b2, a2, E);
  node_kernel<8,64><<<(N*64 + 255)/256, 256, 0, stream>>>(a2, a1, root2, cb2, N);

  conv_mfma<64,128,4,32><<<(Epad/64)*2, 256, 0, stream>>>(ef3b, a2, ei, w2p3, en3_b2, a3, E);
  node3_pool<<<(N + 15)/16, 256, 0, stream>>>(a3, a2, root3, cb3, batch, g, N);

  head_kernel<<<G, 128, 0, stream>>>(g, fc1w, fc1b, fc2w, fc2b, fc3w, fc3b, out);
}